// Round 1
// baseline (730.344 us; speedup 1.0000x reference)
//
#include <hip/hip_runtime.h>
#include <hip/hip_bf16.h>

typedef __attribute__((ext_vector_type(8))) short short8;
typedef __attribute__((ext_vector_type(4))) float f32x4;

#define LDS_BYTES 62464

__device__ __forceinline__ unsigned short f2bf(float x){
  unsigned u = __float_as_uint(x);
  u += 0x7FFFu + ((u >> 16) & 1u);
  return (unsigned short)(u >> 16);
}

// ---------------- weight pre-pack: fp32 [K][N] -> bf16 MFMA B-fragments ----------------
// frag layout: 64 lanes x 8 bf16, lane reads W[kf*32 + (lane>>4)*8 + j][nt*16 + (lane&15)]
// frag index map: qkv: nt*3+kf (54) | out: 54+nt*3+kf (18) | ffn1: 72+nt*3+kf (36) | ffn2: 108+nt*6+kf (36)
__global__ void pack_weights(const float* __restrict__ qkv_w, const float* __restrict__ out_w,
                             const float* __restrict__ ffn_w1, const float* __restrict__ ffn_w2,
                             short8* __restrict__ wsv){
  int f = blockIdx.x, lane = threadIdx.x;
  const float* W; int N, nt, kf;
  if (f < 54)      { W = qkv_w;  N = 288; nt = f/3;        kf = f%3; }
  else if (f < 72) { int i=f-54;  W = out_w;  N = 96;  nt = i/3; kf = i%3; }
  else if (f < 108){ int i=f-72;  W = ffn_w1; N = 192; nt = i/3; kf = i%3; }
  else             { int i=f-108; W = ffn_w2; N = 96;  nt = i/6; kf = i%6; }
  int n = lane & 15, kq = lane >> 4;
  short8 v;
#pragma unroll
  for (int j = 0; j < 8; ++j){
    int k = kf*32 + kq*8 + j;
    v[j] = (short)f2bf(W[(size_t)k * N + nt*16 + n]);
  }
  wsv[f*64 + lane] = v;
}

// ---------------- fused block kernel ----------------
// block = 256 thr (4 waves); handles windows 3g..3g+2 = unique tokens 24g..24g+31 (exact: 1023=3*341)
__global__ __launch_bounds__(256, 2)
void fused_block(const float* __restrict__ x,
                 const float* __restrict__ ln1_g, const float* __restrict__ ln1_b,
                 const float* __restrict__ qkv_b,
                 const float* __restrict__ out_b,
                 const float* __restrict__ ln2_g, const float* __restrict__ ln2_b,
                 const float* __restrict__ ffn_b1, const float* __restrict__ ffn_b2,
                 const float* __restrict__ pln_g, const float* __restrict__ pln_b,
                 const short8* __restrict__ wsv,
                 float* __restrict__ out)
{
  __shared__ __align__(16) char smem[LDS_BYTES];
  float*          hres = (float*)smem;                          // [48][100] fp32 residual trunk
  unsigned short* buf1 = (unsigned short*)(smem + 19200);       // hln[32][104] -> o[48][104] -> f1[48][200]
  unsigned short* buf2 = (unsigned short*)(smem + 38400);       // q[32][104]|k[32][104]|vT[6][16][40] -> h2[48][104]
  unsigned short* Pb   = (unsigned short*)(smem + 59392);       // [4 waves][16][24] softmax scratch

  const int tid  = threadIdx.x;
  const int wave = tid >> 6, lane = tid & 63;
  const int lm   = lane & 15, quad = lane >> 4;
  const int g = blockIdx.x, b = blockIdx.y;
  const int t0 = 24 * g;
  const size_t xbase = ((size_t)b * 8192 + t0) * 96;

  const int KOFF = 3328;   // elems: k region in buf2
  const int VOFF = 6656;   // elems: vT region in buf2

  // ---------- LN1 over 32 unique tokens -> hln bf16 (buf1, stride 104)
  {
    const int r16 = tid >> 4, c0 = tid & 15;
#pragma unroll
    for (int p = 0; p < 2; ++p){
      int row = p*16 + r16;
      float v[6];
#pragma unroll
      for (int e = 0; e < 6; ++e) v[e] = x[xbase + (size_t)row*96 + c0 + 16*e];
      float s = 0.f, q2 = 0.f;
#pragma unroll
      for (int e = 0; e < 6; ++e){ s += v[e]; q2 += v[e]*v[e]; }
#pragma unroll
      for (int m = 1; m < 16; m <<= 1){ s += __shfl_xor(s, m, 16); q2 += __shfl_xor(q2, m, 16); }
      float mean = s * (1.f/96.f);
      float var  = q2 * (1.f/96.f) - mean*mean;
      float rstd = rsqrtf(var + 1e-5f);
#pragma unroll
      for (int e = 0; e < 6; ++e){
        int c = c0 + 16*e;
        buf1[row*104 + c] = f2bf((v[e] - mean) * rstd * ln1_g[c] + ln1_b[c]);
      }
    }
  }
  __syncthreads();

  // ---------- QKV: M=32 (2 mt) x N=288 (18 nt), K=96 -> q,k bf16 [tok][col], v transposed [h][d][tok]
  for (int tile = wave; tile < 36; tile += 4){
    int mt = tile & 1, nt = tile >> 1;
    f32x4 acc = {0.f,0.f,0.f,0.f};
#pragma unroll
    for (int kf = 0; kf < 3; ++kf){
      short8 a = *(const short8*)(buf1 + (16*mt + lm)*104 + kf*32 + quad*8);
      short8 w = wsv[(nt*3 + kf)*64 + lane];
      acc = __builtin_amdgcn_mfma_f32_16x16x32_bf16(a, w, acc, 0, 0, 0);
    }
    int col = nt*16 + lm;
    float bias = qkv_b[col];
#pragma unroll
    for (int r = 0; r < 4; ++r){
      int tok = 16*mt + quad*4 + r;
      unsigned short bv = f2bf(acc[r] + bias);
      if (col < 96)       buf2[tok*104 + col] = bv;                    // q
      else if (col < 192) buf2[KOFF + tok*104 + (col - 96)] = bv;      // k
      else { int d2 = col - 192; buf2[VOFF + ((d2 >> 4)*16 + (d2 & 15))*40 + tok] = bv; } // vT
    }
  }
  __syncthreads();

  // ---------- attention: 18 units (3 windows x 6 heads), K=16 zero-padded to 32
  for (int u = wave; u < 18; u += 4){
    int w = u / 6, h = u % 6;
    short8 qa = {0,0,0,0,0,0,0,0}, ka = {0,0,0,0,0,0,0,0};
    if (quad < 2){
      qa = *(const short8*)(buf2 +        (8*w + lm)*104 + h*16 + quad*8);
      ka = *(const short8*)(buf2 + KOFF + (8*w + lm)*104 + h*16 + quad*8);
    }
    f32x4 sc = {0.f,0.f,0.f,0.f};
    sc = __builtin_amdgcn_mfma_f32_16x16x32_bf16(qa, ka, sc, 0, 0, 0);
    // rows quad*4+r spread over 16 lanes (col = key = lm); causal mask + softmax per row
#pragma unroll
    for (int r = 0; r < 4; ++r){
      int row = quad*4 + r;
      float s = (lm <= row) ? sc[r]*0.25f : -1e30f;
      float mx = s;
#pragma unroll
      for (int m = 1; m < 16; m <<= 1) mx = fmaxf(mx, __shfl_xor(mx, m, 16));
      float p = __expf(s - mx);
      float sum = p;
#pragma unroll
      for (int m = 1; m < 16; m <<= 1) sum += __shfl_xor(sum, m, 16);
      Pb[wave*384 + row*24 + lm] = f2bf(p / sum);
    }
    asm volatile("s_waitcnt lgkmcnt(0)" ::: "memory");
    short8 pa = {0,0,0,0,0,0,0,0}, va = {0,0,0,0,0,0,0,0};
    if (quad < 2){
      pa = *(const short8*)(Pb + wave*384 + lm*24 + quad*8);
      va = *(const short8*)(buf2 + VOFF + (h*16 + lm)*40 + 8*w + quad*8);
    }
    f32x4 oc = {0.f,0.f,0.f,0.f};
    oc = __builtin_amdgcn_mfma_f32_16x16x32_bf16(pa, va, oc, 0, 0, 0);
#pragma unroll
    for (int r = 0; r < 4; ++r)
      buf1[(w*16 + quad*4 + r)*104 + h*16 + lm] = f2bf(oc[r]);   // o (overwrites dead hln)
  }
  __syncthreads();

  // ---------- out-proj + residual: 18 tiles (3 w x 6 nt), K=96 -> hres fp32
  for (int tile = wave; tile < 18; tile += 4){
    int w = tile / 6, nt = tile % 6;
    f32x4 acc = {0.f,0.f,0.f,0.f};
#pragma unroll
    for (int kf = 0; kf < 3; ++kf){
      short8 a = *(const short8*)(buf1 + (w*16 + lm)*104 + kf*32 + quad*8);
      short8 wt = wsv[(54 + nt*3 + kf)*64 + lane];
      acc = __builtin_amdgcn_mfma_f32_16x16x32_bf16(a, wt, acc, 0, 0, 0);
    }
    int col = nt*16 + lm;
    float bias = out_b[col];
#pragma unroll
    for (int r = 0; r < 4; ++r){
      int i = quad*4 + r;                 // token-in-window
      float seg = x[xbase + (size_t)(8*w + i)*96 + col];
      hres[(w*16 + i)*100 + col] = acc[r] + bias + seg;
    }
  }
  __syncthreads();

  // ---------- LN2: 48 rows -> h2 bf16 (buf2, stride 104; q/k/vT dead)
  {
    const int r16 = tid >> 4, c0 = tid & 15;
#pragma unroll
    for (int p = 0; p < 3; ++p){
      int row = p*16 + r16;
      float v[6];
#pragma unroll
      for (int e = 0; e < 6; ++e) v[e] = hres[row*100 + c0 + 16*e];
      float s = 0.f, q2 = 0.f;
#pragma unroll
      for (int e = 0; e < 6; ++e){ s += v[e]; q2 += v[e]*v[e]; }
#pragma unroll
      for (int m = 1; m < 16; m <<= 1){ s += __shfl_xor(s, m, 16); q2 += __shfl_xor(q2, m, 16); }
      float mean = s * (1.f/96.f);
      float rstd = rsqrtf(q2 * (1.f/96.f) - mean*mean + 1e-5f);
#pragma unroll
      for (int e = 0; e < 6; ++e){
        int c = c0 + 16*e;
        buf2[row*104 + c] = f2bf((v[e] - mean) * rstd * ln2_g[c] + ln2_b[c]);
      }
    }
  }
  __syncthreads();

  // ---------- FFN1 + gelu(tanh approx): 36 tiles (3 mt x 12 nt), K=96 -> f1 bf16 (buf1, stride 200)
  for (int tile = wave; tile < 36; tile += 4){
    int mt = tile % 3, nt = tile / 3;
    f32x4 acc = {0.f,0.f,0.f,0.f};
#pragma unroll
    for (int kf = 0; kf < 3; ++kf){
      short8 a = *(const short8*)(buf2 + (mt*16 + lm)*104 + kf*32 + quad*8);
      short8 wt = wsv[(72 + nt*3 + kf)*64 + lane];
      acc = __builtin_amdgcn_mfma_f32_16x16x32_bf16(a, wt, acc, 0, 0, 0);
    }
    int col = nt*16 + lm;
    float bias = ffn_b1[col];
#pragma unroll
    for (int r = 0; r < 4; ++r){
      float u = acc[r] + bias;
      float z = 0.7978845608f * (u + 0.044715f * u*u*u);
      z = fminf(fmaxf(z, -10.f), 10.f);
      float e2 = __expf(2.f * z);
      float th = (e2 - 1.f) / (e2 + 1.f);
      buf1[(mt*16 + quad*4 + r)*200 + col] = f2bf(0.5f * u * (1.f + th));
    }
  }
  __syncthreads();

  // ---------- FFN2 + residual: 18 tiles (3 mt x 6 nt), K=192 -> hres (in place)
  for (int tile = wave; tile < 18; tile += 4){
    int mt = tile / 6, nt = tile % 6;
    f32x4 acc = {0.f,0.f,0.f,0.f};
#pragma unroll
    for (int kf = 0; kf < 6; ++kf){
      short8 a = *(const short8*)(buf1 + (mt*16 + lm)*200 + kf*32 + quad*8);
      short8 wt = wsv[(108 + nt*6 + kf)*64 + lane];
      acc = __builtin_amdgcn_mfma_f32_16x16x32_bf16(a, wt, acc, 0, 0, 0);
    }
    int col = nt*16 + lm;
    float bias = ffn_b2[col];
#pragma unroll
    for (int r = 0; r < 4; ++r){
      int row = mt*16 + quad*4 + r;
      hres[row*100 + col] += acc[r] + bias;
    }
  }
  __syncthreads();

  // ---------- post-LN + scaled scatter-add
  {
    const int r16 = tid >> 4, c0 = tid & 15;
#pragma unroll
    for (int p = 0; p < 3; ++p){
      int row = p*16 + r16;
      float v[6];
#pragma unroll
      for (int e = 0; e < 6; ++e) v[e] = hres[row*100 + c0 + 16*e];
      float s = 0.f, q2 = 0.f;
#pragma unroll
      for (int e = 0; e < 6; ++e){ s += v[e]; q2 += v[e]*v[e]; }
#pragma unroll
      for (int m = 1; m < 16; m <<= 1){ s += __shfl_xor(s, m, 16); q2 += __shfl_xor(q2, m, 16); }
      float mean = s * (1.f/96.f);
      float rstd = rsqrtf(q2 * (1.f/96.f) - mean*mean + 1e-5f);
      int l = t0 + 8*(row >> 4) + (row & 15);
      float inv = (l < 8 || l >= 8184) ? 1.0f : 0.5f;
      size_t obase = ((size_t)b * 8192 + l) * 96;
#pragma unroll
      for (int e = 0; e < 6; ++e){
        int c = c0 + 16*e;
        float val = ((v[e] - mean) * rstd * pln_g[c] + pln_b[c]) * inv;
        atomicAdd(&out[obase + c], val);
      }
    }
  }
}

extern "C" void kernel_launch(void* const* d_in, const int* in_sizes, int n_in,
                              void* d_out, int out_size, void* d_ws, size_t ws_size,
                              hipStream_t stream) {
  const float* x      = (const float*)d_in[0];
  const float* ln1_g  = (const float*)d_in[1];
  const float* ln1_b  = (const float*)d_in[2];
  const float* qkv_w  = (const float*)d_in[3];
  const float* qkv_b  = (const float*)d_in[4];
  const float* out_w  = (const float*)d_in[5];
  const float* out_b  = (const float*)d_in[6];
  const float* ln2_g  = (const float*)d_in[7];
  const float* ln2_b  = (const float*)d_in[8];
  const float* ffn_w1 = (const float*)d_in[9];
  const float* ffn_b1 = (const float*)d_in[10];
  const float* ffn_w2 = (const float*)d_in[11];
  const float* ffn_b2 = (const float*)d_in[12];
  const float* pln_g  = (const float*)d_in[13];
  const float* pln_b  = (const float*)d_in[14];
  float* out = (float*)d_out;
  short8* wsv = (short8*)d_ws;

  hipMemsetAsync(d_out, 0, (size_t)out_size * sizeof(float), stream);
  pack_weights<<<144, 64, 0, stream>>>(qkv_w, out_w, ffn_w1, ffn_w2, wsv);
  fused_block<<<dim3(341, 32), 256, 0, stream>>>(
      x, ln1_g, ln1_b, qkv_b, out_b, ln2_g, ln2_b, ffn_b1, ffn_b2,
      pln_g, pln_b, (const short8*)wsv, out);
}

// Round 2
// 479.310 us; speedup vs baseline: 1.5237x; 1.5237x over previous
//
#include <hip/hip_runtime.h>
#include <hip/hip_bf16.h>

typedef __attribute__((ext_vector_type(8))) short short8;
typedef __attribute__((ext_vector_type(4))) float f32x4;

#define LDS_BYTES 50176

__device__ __forceinline__ unsigned short f2bf(float x){
  unsigned u = __float_as_uint(x);
  u += 0x7FFFu + ((u >> 16) & 1u);
  return (unsigned short)(u >> 16);
}

// ---------------- weight pre-pack: fp32 [K][N] -> bf16 MFMA B-fragments ----------------
// frag layout: 64 lanes x 8 bf16, lane reads W[kf*32 + (lane>>4)*8 + j][nt*16 + (lane&15)]
// frag index map: qkv: nt*3+kf (54) | out: 54+nt*3+kf (18) | ffn1: 72+nt*3+kf (36) | ffn2: 108+nt*6+kf (36)
__global__ void pack_weights(const float* __restrict__ qkv_w, const float* __restrict__ out_w,
                             const float* __restrict__ ffn_w1, const float* __restrict__ ffn_w2,
                             short8* __restrict__ wsv){
  int f = blockIdx.x, lane = threadIdx.x;
  const float* W; int N, nt, kf;
  if (f < 54)      { W = qkv_w;  N = 288; nt = f/3;        kf = f%3; }
  else if (f < 72) { int i=f-54;  W = out_w;  N = 96;  nt = i/3; kf = i%3; }
  else if (f < 108){ int i=f-72;  W = ffn_w1; N = 192; nt = i/3; kf = i%3; }
  else             { int i=f-108; W = ffn_w2; N = 96;  nt = i/6; kf = i%6; }
  int n = lane & 15, kq = lane >> 4;
  short8 v;
#pragma unroll
  for (int j = 0; j < 8; ++j){
    int k = kf*32 + kq*8 + j;
    v[j] = (short)f2bf(W[(size_t)k * N + nt*16 + n]);
  }
  wsv[f*64 + lane] = v;
}

// ---------------- fused block kernel ----------------
// 512 thr (8 waves); windows 3g..3g+2 = unique tokens 24g..24g+31 (exact: 1023=3*341)
// LDS 50176 B -> 3 blocks/CU (24 waves/CU) with launch_bounds(512,6)
__global__ __launch_bounds__(512, 6)
void fused_block(const float* __restrict__ x,
                 const float* __restrict__ ln1_g, const float* __restrict__ ln1_b,
                 const float* __restrict__ qkv_b,
                 const float* __restrict__ out_b,
                 const float* __restrict__ ln2_g, const float* __restrict__ ln2_b,
                 const float* __restrict__ ffn_b1, const float* __restrict__ ffn_b2,
                 const float* __restrict__ pln_g, const float* __restrict__ pln_b,
                 const short8* __restrict__ wsv,
                 float* __restrict__ out)
{
  __shared__ __align__(16) char smem[LDS_BYTES];
  float*          hres = (float*)smem;                          // [48][100] fp32 residual trunk
  unsigned short* Pb   = (unsigned short*)smem;                 // overlay: [8 waves][16][24] softmax scratch (attn phase only)
  unsigned short* buf1 = (unsigned short*)(smem + 19200);       // [48][104]: hln(32 rows) -> o -> f1half
  unsigned short* buf2 = (unsigned short*)(smem + 29184);       // q[32][104]|k[32][104]|vT[96][40] -> h2[48][104]

  const int tid  = threadIdx.x;
  const int wave = tid >> 6, lane = tid & 63;
  const int lm   = lane & 15, quad = lane >> 4;
  const int g = blockIdx.x, b = blockIdx.y;
  const int t0 = 24 * g;
  const size_t xbase = ((size_t)b * 8192 + t0) * 96;

  const int KOFF = 3328;   // elems: k region in buf2
  const int VOFF = 6656;   // elems: vT region in buf2

  // ---------- LN1 over 32 unique tokens -> hln bf16 (buf1, stride 104)
  {
    const int row = tid >> 4, c0 = tid & 15;    // 512 thr -> all 32 rows in one pass
    float v[6];
#pragma unroll
    for (int e = 0; e < 6; ++e) v[e] = x[xbase + (size_t)row*96 + c0 + 16*e];
    float s = 0.f, q2 = 0.f;
#pragma unroll
    for (int e = 0; e < 6; ++e){ s += v[e]; q2 += v[e]*v[e]; }
#pragma unroll
    for (int m = 1; m < 16; m <<= 1){ s += __shfl_xor(s, m, 16); q2 += __shfl_xor(q2, m, 16); }
    float mean = s * (1.f/96.f);
    float rstd = rsqrtf(q2 * (1.f/96.f) - mean*mean + 1e-5f);
#pragma unroll
    for (int e = 0; e < 6; ++e){
      int c = c0 + 16*e;
      buf1[row*104 + c] = f2bf((v[e] - mean) * rstd * ln1_g[c] + ln1_b[c]);
    }
  }
  __syncthreads();

  // ---------- QKV: M=32 (2 mt) x N=288 (18 nt), K=96; q,k token-major, v transposed [d][tok]
  for (int tile = wave; tile < 36; tile += 8){
    int mt = tile & 1, nt = tile >> 1;
    f32x4 acc = {0.f,0.f,0.f,0.f};
#pragma unroll
    for (int kf = 0; kf < 3; ++kf){
      short8 a = *(const short8*)(buf1 + (16*mt + lm)*104 + kf*32 + quad*8);
      short8 w = wsv[(nt*3 + kf)*64 + lane];
      acc = __builtin_amdgcn_mfma_f32_16x16x32_bf16(a, w, acc, 0, 0, 0);
    }
    int col = nt*16 + lm;
    float bias = qkv_b[col];
    if (nt < 6){                          // q  (wave-uniform branch)
#pragma unroll
      for (int r = 0; r < 4; ++r){
        int tok = 16*mt + quad*4 + r;
        buf2[tok*104 + col] = f2bf(acc[r] + bias);
      }
    } else if (nt < 12){                  // k
      int cl = col - 96;
#pragma unroll
      for (int r = 0; r < 4; ++r){
        int tok = 16*mt + quad*4 + r;
        buf2[KOFF + tok*104 + cl] = f2bf(acc[r] + bias);
      }
    } else {                              // v -> vT[d][tok]
      int d2 = col - 192;
#pragma unroll
      for (int r = 0; r < 4; ++r){
        int tok = 16*mt + quad*4 + r;
        buf2[VOFF + d2*40 + tok] = f2bf(acc[r] + bias);
      }
    }
  }
  __syncthreads();

  // ---------- attention: 18 units (3 windows x 6 heads), K=16 zero-padded to 32
  for (int u = wave; u < 18; u += 8){
    int w = u / 6, h = u % 6;
    short8 qa = {0,0,0,0,0,0,0,0}, ka = {0,0,0,0,0,0,0,0};
    if (quad < 2){
      qa = *(const short8*)(buf2 +        (8*w + lm)*104 + h*16 + quad*8);
      ka = *(const short8*)(buf2 + KOFF + (8*w + lm)*104 + h*16 + quad*8);
    }
    f32x4 sc = {0.f,0.f,0.f,0.f};
    sc = __builtin_amdgcn_mfma_f32_16x16x32_bf16(qa, ka, sc, 0, 0, 0);
#pragma unroll
    for (int r = 0; r < 4; ++r){
      int row = quad*4 + r;
      float s = (lm <= row) ? sc[r]*0.25f : -1e30f;
      float mx = s;
#pragma unroll
      for (int m = 1; m < 16; m <<= 1) mx = fmaxf(mx, __shfl_xor(mx, m, 16));
      float p = __expf(s - mx);
      float sum = p;
#pragma unroll
      for (int m = 1; m < 16; m <<= 1) sum += __shfl_xor(sum, m, 16);
      Pb[wave*384 + row*24 + lm] = f2bf(p / sum);
    }
    asm volatile("s_waitcnt lgkmcnt(0)" ::: "memory");
    short8 pa = {0,0,0,0,0,0,0,0}, va = {0,0,0,0,0,0,0,0};
    if (quad < 2){
      pa = *(const short8*)(Pb + wave*384 + lm*24 + quad*8);
      va = *(const short8*)(buf2 + VOFF + (h*16 + lm)*40 + 8*w + quad*8);
    }
    f32x4 oc = {0.f,0.f,0.f,0.f};
    oc = __builtin_amdgcn_mfma_f32_16x16x32_bf16(pa, va, oc, 0, 0, 0);
#pragma unroll
    for (int r = 0; r < 4; ++r)
      buf1[(w*16 + quad*4 + r)*104 + h*16 + lm] = f2bf(oc[r]);   // o (hln dead)
  }
  __syncthreads();

  // ---------- out-proj + residual: 18 tiles (3 w x 6 nt), K=96 -> hres fp32 (Pb dead)
  for (int tile = wave; tile < 18; tile += 8){
    int w = tile / 6, nt = tile % 6;
    f32x4 acc = {0.f,0.f,0.f,0.f};
#pragma unroll
    for (int kf = 0; kf < 3; ++kf){
      short8 a = *(const short8*)(buf1 + (w*16 + lm)*104 + kf*32 + quad*8);
      short8 wt = wsv[(54 + nt*3 + kf)*64 + lane];
      acc = __builtin_amdgcn_mfma_f32_16x16x32_bf16(a, wt, acc, 0, 0, 0);
    }
    int col = nt*16 + lm;
    float bias = out_b[col];
#pragma unroll
    for (int r = 0; r < 4; ++r){
      int i = quad*4 + r;
      float seg = x[xbase + (size_t)(8*w + i)*96 + col];
      hres[(w*16 + i)*100 + col] = acc[r] + bias + seg;
    }
  }
  __syncthreads();

  // ---------- LN2: 48 rows -> h2 bf16 (buf2; q/k/vT dead)
  {
    const int r16 = tid >> 4, c0 = tid & 15;
#pragma unroll
    for (int p = 0; p < 2; ++p){
      int row = p*32 + r16;
      if (row < 48){
        float v[6];
#pragma unroll
        for (int e = 0; e < 6; ++e) v[e] = hres[row*100 + c0 + 16*e];
        float s = 0.f, q2 = 0.f;
#pragma unroll
        for (int e = 0; e < 6; ++e){ s += v[e]; q2 += v[e]*v[e]; }
#pragma unroll
        for (int m = 1; m < 16; m <<= 1){ s += __shfl_xor(s, m, 16); q2 += __shfl_xor(q2, m, 16); }
        float mean = s * (1.f/96.f);
        float rstd = rsqrtf(q2 * (1.f/96.f) - mean*mean + 1e-5f);
#pragma unroll
        for (int e = 0; e < 6; ++e){
          int c = c0 + 16*e;
          buf2[row*104 + c] = f2bf((v[e] - mean) * rstd * ln2_g[c] + ln2_b[c]);
        }
      }
    }
  }

  // ---------- FFN in two 96-col halves; FFN2 partials in registers
  f32x4 facc0 = {0.f,0.f,0.f,0.f}, facc1 = {0.f,0.f,0.f,0.f}, facc2 = {0.f,0.f,0.f,0.f};
#pragma unroll
  for (int h = 0; h < 2; ++h){
    __syncthreads();   // h=0: h2 ready & o dead; h=1: prev FFN2 half done reading f1
    // FFN1 half: 18 tiles (3 mt x 6 local nt), K=96, gelu -> buf1 [48][104]
    for (int tile = wave; tile < 18; tile += 8){
      int mt = tile % 3, ntl = tile / 3;
      int ng = 6*h + ntl;
      f32x4 acc = {0.f,0.f,0.f,0.f};
#pragma unroll
      for (int kf = 0; kf < 3; ++kf){
        short8 a = *(const short8*)(buf2 + (mt*16 + lm)*104 + kf*32 + quad*8);
        short8 wt = wsv[(72 + ng*3 + kf)*64 + lane];
        acc = __builtin_amdgcn_mfma_f32_16x16x32_bf16(a, wt, acc, 0, 0, 0);
      }
      float bias = ffn_b1[ng*16 + lm];
#pragma unroll
      for (int r = 0; r < 4; ++r){
        float u = acc[r] + bias;
        float z = 0.7978845608f * (u + 0.044715f * u*u*u);
        z = fminf(fmaxf(z, -10.f), 10.f);
        float e2 = __expf(2.f * z);
        float th = (e2 - 1.f) / (e2 + 1.f);
        buf1[(mt*16 + quad*4 + r)*104 + ntl*16 + lm] = f2bf(0.5f * u * (1.f + th));
      }
    }
    __syncthreads();
    // FFN2 partial: 18 tiles (3 mt x 6 nt), local K=96 (global k = 96h..96h+95)
    int s2 = 0;
    for (int tile = wave; tile < 18; tile += 8, ++s2){
      int mt = tile / 6, nt = tile % 6;
      f32x4 acc = (s2 == 0) ? facc0 : (s2 == 1) ? facc1 : facc2;
#pragma unroll
      for (int kf = 0; kf < 3; ++kf){
        short8 a = *(const short8*)(buf1 + (mt*16 + lm)*104 + kf*32 + quad*8);
        short8 wt = wsv[(108 + nt*6 + 3*h + kf)*64 + lane];
        acc = __builtin_amdgcn_mfma_f32_16x16x32_bf16(a, wt, acc, 0, 0, 0);
      }
      if (s2 == 0) facc0 = acc; else if (s2 == 1) facc1 = acc; else facc2 = acc;
    }
  }
  // FFN2 writeback + residual into hres
  {
    int s2 = 0;
    for (int tile = wave; tile < 18; tile += 8, ++s2){
      int mt = tile / 6, nt = tile % 6;
      int col = nt*16 + lm;
      float bias = ffn_b2[col];
      f32x4 acc = (s2 == 0) ? facc0 : (s2 == 1) ? facc1 : facc2;
#pragma unroll
      for (int r = 0; r < 4; ++r)
        hres[(mt*16 + quad*4 + r)*100 + col] += acc[r] + bias;
    }
  }
  __syncthreads();

  // ---------- post-LN (in place on hres)
  {
    const int r16 = tid >> 4, c0 = tid & 15;
#pragma unroll
    for (int p = 0; p < 2; ++p){
      int row = p*32 + r16;
      if (row < 48){
        float v[6];
#pragma unroll
        for (int e = 0; e < 6; ++e) v[e] = hres[row*100 + c0 + 16*e];
        float s = 0.f, q2 = 0.f;
#pragma unroll
        for (int e = 0; e < 6; ++e){ s += v[e]; q2 += v[e]*v[e]; }
#pragma unroll
        for (int m = 1; m < 16; m <<= 1){ s += __shfl_xor(s, m, 16); q2 += __shfl_xor(q2, m, 16); }
        float mean = s * (1.f/96.f);
        float rstd = rsqrtf(q2 * (1.f/96.f) - mean*mean + 1e-5f);
#pragma unroll
        for (int e = 0; e < 6; ++e){
          int c = c0 + 16*e;
          hres[row*100 + c] = (v[e] - mean) * rstd * pln_g[c] + pln_b[c];
        }
      }
    }
  }
  __syncthreads();

  // ---------- combine window copies per unique token; plain-store middle, atomic edges
  {
    const int i = tid >> 4, c0 = tid & 15;     // token-in-group 0..31
    const int l = t0 + i;
    const size_t obase = ((size_t)b * 8192 + l) * 96;
    int rowA, rowB = -1;
    if (i < 8)       rowA = i;                                   // window 0 only
    else if (i < 16){ rowA = i;            rowB = 16 + (i - 8);} // windows 0,1
    else if (i < 24){ rowA = 16 + (i - 8); rowB = 32 + (i - 16);}// windows 1,2
    else             rowA = 32 + (i - 16);                       // window 2 only
    if (rowB >= 0){                       // middle: both contributors in-block, cnt==2
#pragma unroll
      for (int e = 0; e < 6; ++e){
        int c = c0 + 16*e;
        out[obase + c] = 0.5f * (hres[rowA*100 + c] + hres[rowB*100 + c]);
      }
    } else {                              // edge: one in-block row; neighbor block adds
      float inv = (l < 8 || l >= 8184) ? 1.0f : 0.5f;
#pragma unroll
      for (int e = 0; e < 6; ++e){
        int c = c0 + 16*e;
        atomicAdd(&out[obase + c], hres[rowA*100 + c] * inv);
      }
    }
  }
}

extern "C" void kernel_launch(void* const* d_in, const int* in_sizes, int n_in,
                              void* d_out, int out_size, void* d_ws, size_t ws_size,
                              hipStream_t stream) {
  const float* x      = (const float*)d_in[0];
  const float* ln1_g  = (const float*)d_in[1];
  const float* ln1_b  = (const float*)d_in[2];
  const float* qkv_w  = (const float*)d_in[3];
  const float* qkv_b  = (const float*)d_in[4];
  const float* out_w  = (const float*)d_in[5];
  const float* out_b  = (const float*)d_in[6];
  const float* ln2_g  = (const float*)d_in[7];
  const float* ln2_b  = (const float*)d_in[8];
  const float* ffn_w1 = (const float*)d_in[9];
  const float* ffn_b1 = (const float*)d_in[10];
  const float* ffn_w2 = (const float*)d_in[11];
  const float* ffn_b2 = (const float*)d_in[12];
  const float* pln_g  = (const float*)d_in[13];
  const float* pln_b  = (const float*)d_in[14];
  float* out = (float*)d_out;
  short8* wsv = (short8*)d_ws;

  hipMemsetAsync(d_out, 0, (size_t)out_size * sizeof(float), stream);
  pack_weights<<<144, 64, 0, stream>>>(qkv_w, out_w, ffn_w1, ffn_w2, wsv);
  fused_block<<<dim3(341, 32), 512, 0, stream>>>(
      x, ln1_g, ln1_b, qkv_b, out_b, ln2_g, ln2_b, ffn_b1, ffn_b2,
      pln_g, pln_b, (const short8*)wsv, out);
}